// Round 1
// baseline (774.029 us; speedup 1.0000x reference)
//
#include <hip/hip_runtime.h>

#define B_ 4
#define N_ 16384
#define HID_ 512
#define H_ 8
#define M_ 32
#define D_ 64

typedef __attribute__((ext_vector_type(8))) short short8;
typedef __attribute__((ext_vector_type(4))) float f32x4;

__device__ __forceinline__ short f2bf(float f) {
    unsigned u = __float_as_uint(f);
    u += 0x7fffu + ((u >> 16) & 1u);
    return (short)(u >> 16);
}
__device__ __forceinline__ float bf2f(short s) {
    return __uint_as_float(((unsigned)(unsigned short)s) << 16);
}
__device__ __forceinline__ unsigned pack2(float a, float b) {
    return (unsigned)(unsigned short)f2bf(a) | ((unsigned)(unsigned short)f2bf(b) << 16);
}

// ---------------------------------------------------------------- misc outputs
__global__ void k_misc(const float* __restrict__ alpha, float* __restrict__ a_out,
                       float* __restrict__ z_out) {
    int t = threadIdx.x;
    if (t < H_) a_out[t] = alpha[t];
    z_out[t] = 0.f;  // 256 = H_*M_
}

// ------------------------------------------- wkv_w (512x1024 f32) -> (1024x512 bf16)
__global__ void k_wt(const float* __restrict__ w, short* __restrict__ wt) {
    int e = blockIdx.x * 256 + threadIdx.x;   // 524288 total
    int nn = e >> 9, kk = e & 511;
    wt[e] = f2bf(w[kk * 1024 + nn]);
}

// ---------------------------------------------------------------- MFMA GEMM
// C (Mrows x Ncols) = A (Mrows x K) * Bt^T  (Bt stored N x K, bf16) + bias
// A either f32 (converted during staging) or bf16. 128x128 block tile, BK=32.
template <bool A_F32, bool OUT_BF16>
__global__ __launch_bounds__(256, 2)
void mfma_gemm(const void* __restrict__ Av, const short* __restrict__ Bt,
               const float* __restrict__ bias, void* __restrict__ Cv,
               int K, int Ncols, int b_stride, int rows_per_b) {
    __shared__ short As[128 * 32];
    __shared__ short Bs[128 * 32];
    const int t = threadIdx.x;
    const int row0 = blockIdx.x * 128;
    const int col0 = blockIdx.y * 128;
    const short* Bblk = Bt;
    if (b_stride) Bblk += (size_t)(row0 / rows_per_b) * (size_t)b_stride;

    const int w = t >> 6;
    const int L = t & 63;
    const int wm = (w >> 1) << 6;
    const int wn = (w & 1) << 6;
    const int lm = L & 15;
    const int lq = L >> 4;

    f32x4 acc[4][4];
#pragma unroll
    for (int i = 0; i < 4; ++i)
#pragma unroll
        for (int j = 0; j < 4; ++j) acc[i][j] = (f32x4){0.f, 0.f, 0.f, 0.f};

    for (int k0 = 0; k0 < K; k0 += 32) {
#pragma unroll
        for (int p = 0; p < 2; ++p) {
            const int e = ((p << 8) + t) << 3;  // element index, 8 per thread
            const int r = e >> 5;
            const int c = e & 31;
            if constexpr (A_F32) {
                const float* src = (const float*)Av + (size_t)(row0 + r) * K + (k0 + c);
                f32x4 v0 = *(const f32x4*)src;
                f32x4 v1 = *(const f32x4*)(src + 4);
                short8 o;
                o[0] = f2bf(v0[0]); o[1] = f2bf(v0[1]); o[2] = f2bf(v0[2]); o[3] = f2bf(v0[3]);
                o[4] = f2bf(v1[0]); o[5] = f2bf(v1[1]); o[6] = f2bf(v1[2]); o[7] = f2bf(v1[3]);
                *(short8*)&As[e] = o;
            } else {
                const short* src = (const short*)Av + (size_t)(row0 + r) * K + (k0 + c);
                *(short8*)&As[e] = *(const short8*)src;
            }
            const short* bsrc = Bblk + (size_t)(col0 + r) * K + (k0 + c);
            *(short8*)&Bs[e] = *(const short8*)bsrc;
        }
        __syncthreads();
        short8 af[4], bfr[4];
#pragma unroll
        for (int i = 0; i < 4; ++i)
            af[i] = *(const short8*)&As[((wm + (i << 4) + lm) << 5) + (lq << 3)];
#pragma unroll
        for (int j = 0; j < 4; ++j)
            bfr[j] = *(const short8*)&Bs[((wn + (j << 4) + lm) << 5) + (lq << 3)];
#pragma unroll
        for (int i = 0; i < 4; ++i)
#pragma unroll
            for (int j = 0; j < 4; ++j)
                acc[i][j] = __builtin_amdgcn_mfma_f32_16x16x32_bf16(af[i], bfr[j], acc[i][j], 0, 0, 0);
        __syncthreads();
    }
#pragma unroll
    for (int i = 0; i < 4; ++i) {
#pragma unroll
        for (int j = 0; j < 4; ++j) {
            const int gr = row0 + wm + (i << 4) + (lq << 2);
            const int gc = col0 + wn + (j << 4) + lm;
            const float bv = bias[gc];
#pragma unroll
            for (int r = 0; r < 4; ++r) {
                float v = acc[i][j][r] + bv;
                if constexpr (OUT_BF16)
                    ((short*)Cv)[(size_t)(gr + r) * Ncols + gc] = f2bf(v);
                else
                    ((float*)Cv)[(size_t)(gr + r) * Ncols + gc] = v;
            }
        }
    }
}

// ---------------------------------------------------------------- slice kernel
// Per block: one (b,h) and a 256-token chunk. Computes slice scores, softmax over m,
// writes sw (f32 out) + swT (bf16 ws), accumulates num[b,h,m,d] and wsum[b,h,m].
__global__ __launch_bounds__(256, 2)
void k_slice(const short* __restrict__ kv, const float* __restrict__ wtq,
             const float* __restrict__ alpha, float* __restrict__ sw_out,
             short* __restrict__ swT, float* __restrict__ num, float* __restrict__ wsum) {
    __shared__ float w_s[256 * 32];     // 32 KB
    __shared__ short8 xv_s[256 * 8];    // 32 KB (bf16 xv rows)
    const int t = threadIdx.x;
    const int bx = blockIdx.x;
    const int chunk = bx & 63;
    const int h = (bx >> 6) & 7;
    const int b = bx >> 9;
    const int n = chunk * 256 + t;
    const size_t rowbase = (size_t)(b * N_ + n) * (2 * HID_);

    // stage xv row (bf16, no convert)
    const short8* xvp = (const short8*)(kv + rowbase + HID_ + h * 64);
#pragma unroll
    for (int i = 0; i < 8; ++i) xv_s[t * 8 + i] = xvp[i];

    // xk row into registers
    float x[64];
    const short8* xkp = (const short8*)(kv + rowbase + h * 64);
#pragma unroll
    for (int i = 0; i < 8; ++i) {
        short8 v = xkp[i];
#pragma unroll
        for (int j = 0; j < 8; ++j) x[i * 8 + j] = bf2f(v[j]);
    }

    // scores: wtq reads are block-uniform -> scalar loads
    const float* wq = wtq + h * (M_ * 64);
    float s[32];
#pragma unroll
    for (int m = 0; m < 32; ++m) {
        float a = 0.f;
#pragma unroll
        for (int d = 0; d < 64; ++d) a += wq[m * 64 + d] * x[d];
        s[m] = a;
    }
    const float al = alpha[h];
    float mx = -1e30f;
#pragma unroll
    for (int m = 0; m < 32; ++m) { s[m] *= al; mx = fmaxf(mx, s[m]); }
    float sum = 0.f;
#pragma unroll
    for (int m = 0; m < 32; ++m) { s[m] = __expf(s[m] - mx); sum += s[m]; }
    const float inv = 1.f / sum;

    float* swp = sw_out + (size_t)(b * H_ + h) * M_ * N_ + n;
    short* swtp = swT + (size_t)(b * N_ + n) * (H_ * M_) + h * M_;
    float prev = 0.f;
#pragma unroll
    for (int m = 0; m < 32; ++m) {
        float wv = s[m] * inv;
        swp[(size_t)m * N_] = wv;        // coalesced over t
        w_s[t * 32 + m] = wv;
        if (m & 1) *(unsigned*)(swtp + m - 1) = pack2(prev, wv);
        prev = wv;
    }
    __syncthreads();

    // block-local weighted sum: num[m][d] += sum_t w[t][m] * xv[t][d]
    const int m = t >> 3;
    const int dg = t & 7;
    float acc[8] = {0, 0, 0, 0, 0, 0, 0, 0};
    float wsl = 0.f;
    for (int tt = 0; tt < 256; ++tt) {
        float wv = w_s[tt * 32 + m];       // broadcast (uniform tt)
        short8 v8 = xv_s[tt * 8 + dg];     // conflict-free b128
        wsl += wv;
#pragma unroll
        for (int q = 0; q < 8; ++q) acc[q] += wv * bf2f(v8[q]);
    }
    float* np = num + ((size_t)(b * H_ + h) * M_ + m) * 64 + dg * 8;
#pragma unroll
    for (int q = 0; q < 8; ++q) atomicAdd(np + q, acc[q]);
    if (dg == 0) atomicAdd(wsum + (b * H_ + h) * M_ + m, wsl);
}

// ---------------------------------------------------------------- qkv GEMM (tiny)
// st[m][k] = num/(wsum+1e-5) staged transposed in LDS; qkv = st @ qkv_w (no bias)
__global__ __launch_bounds__(256, 2)
void k_qkv(const float* __restrict__ num, const float* __restrict__ wsum,
           const float* __restrict__ qkv_w, float* __restrict__ qkv) {
    __shared__ float st_s[512 * 32];  // [k][m], 64 KB
    const int t = threadIdx.x;
    const int b = blockIdx.y;
    for (int p = 0; p < 64; ++p) {
        int idx = p * 256 + t;
        int m = idx & 31, k = idx >> 5;
        int h = k >> 6, d = k & 63;
        float wsv = wsum[(b * H_ + h) * M_ + m];
        st_s[k * 32 + m] = num[((size_t)(b * H_ + h) * M_ + m) * 64 + d] / (wsv + 1e-5f);
    }
    __syncthreads();
    const int m = t >> 3;
    const int c0 = blockIdx.x * 64 + (t & 7) * 8;
    float acc[8] = {};
    for (int k = 0; k < 512; ++k) {
        float sv = st_s[k * 32 + m];
        const f32x4* wp = (const f32x4*)(qkv_w + (size_t)k * 1536 + c0);
        f32x4 w0 = wp[0], w1 = wp[1];
        acc[0] += sv * w0[0]; acc[1] += sv * w0[1]; acc[2] += sv * w0[2]; acc[3] += sv * w0[3];
        acc[4] += sv * w1[0]; acc[5] += sv * w1[1]; acc[6] += sv * w1[2]; acc[7] += sv * w1[3];
    }
    float* dst = qkv + (size_t)(b * M_ + m) * 1536 + c0;
#pragma unroll
    for (int i = 0; i < 8; ++i) dst[i] = acc[i];
}

// ---------------------------------------------------------------- MHA (tiny, M=32)
__global__ __launch_bounds__(256)
void k_mha(const float* __restrict__ qkv, float* __restrict__ attn_out,
           float* __restrict__ ot) {
    __shared__ float q_s[32 * 65], k_s[32 * 65], v_s[32 * 65];
    __shared__ float s_s[32 * 33], p_s[32 * 33];
    const int bx = blockIdx.x;
    const int b = bx >> 3, h = bx & 7;
    const int t = threadIdx.x;
    for (int p = 0; p < 8; ++p) {
        int idx = p * 256 + t;
        int m = idx >> 6, d = idx & 63;
        size_t base = (size_t)(b * M_ + m) * 1536 + h * 64 + d;
        q_s[m * 65 + d] = qkv[base];
        k_s[m * 65 + d] = qkv[base + 512];
        v_s[m * 65 + d] = qkv[base + 1024];
    }
    __syncthreads();
    for (int p = 0; p < 4; ++p) {
        int c = p * 256 + t;
        int m = c >> 5, mm = c & 31;
        float a = 0.f;
#pragma unroll
        for (int d = 0; d < 64; ++d) a += q_s[m * 65 + d] * k_s[mm * 65 + d];
        s_s[m * 33 + mm] = a * 0.125f;
    }
    __syncthreads();
    if (t < 32) {
        float mx = -1e30f;
        for (int mm = 0; mm < 32; ++mm) mx = fmaxf(mx, s_s[t * 33 + mm]);
        float sum = 0.f;
        for (int mm = 0; mm < 32; ++mm) {
            float e = __expf(s_s[t * 33 + mm] - mx);
            p_s[t * 33 + mm] = e;
            sum += e;
        }
        float inv = 1.f / sum;
        for (int mm = 0; mm < 32; ++mm) {
            float av = p_s[t * 33 + mm] * inv;
            p_s[t * 33 + mm] = av;
            attn_out[((size_t)(b * H_ + h) * M_ + t) * M_ + mm] = av;
        }
    }
    __syncthreads();
    const int m = t >> 3, d0 = (t & 7) * 8;
    float acc[8] = {};
    for (int mm = 0; mm < 32; ++mm) {
        float av = p_s[m * 33 + mm];
#pragma unroll
        for (int j = 0; j < 8; ++j) acc[j] += av * v_s[mm * 65 + d0 + j];
    }
    float* dst = ot + ((size_t)(b * H_ + h) * M_ + m) * 64 + d0;
#pragma unroll
    for (int j = 0; j < 8; ++j) dst[j] = acc[j];
}

// ------------------------------------- P^T: Pt[b][j][h*32+m] = sum_d ot[m][d]*out_w[h*64+d][j]
__global__ __launch_bounds__(256)
void k_p(const float* __restrict__ ot, const float* __restrict__ out_w,
         short* __restrict__ Pt) {
    __shared__ float ot_s[32 * 65];
    const int bh = blockIdx.y;
    const int b = bh >> 3, h = bh & 7;
    const int t = threadIdx.x;
    for (int p = 0; p < 8; ++p) {
        int idx = p * 256 + t;
        int m = idx >> 6, d = idx & 63;
        ot_s[m * 65 + d] = ot[(size_t)bh * (M_ * 64) + idx];
    }
    __syncthreads();
    const int j = blockIdx.x * 128 + (t & 127);
    const int mh = (t >> 7) * 16;
    float acc[16] = {};
    for (int d = 0; d < 64; ++d) {
        float ow = out_w[(size_t)(h * 64 + d) * HID_ + j];   // coalesced
#pragma unroll
        for (int i = 0; i < 16; ++i) acc[i] += ot_s[(mh + i) * 65 + d] * ow;
    }
    short* dst = Pt + ((size_t)b * HID_ + j) * (H_ * M_) + h * M_ + mh;
#pragma unroll
    for (int i = 0; i < 16; i += 2) *(unsigned*)(dst + i) = pack2(acc[i], acc[i + 1]);
}

// ---------------------------------------------------------------- launcher
extern "C" void kernel_launch(void* const* d_in, const int* in_sizes, int n_in,
                              void* d_out, int out_size, void* d_ws, size_t ws_size,
                              hipStream_t stream) {
    const float* x     = (const float*)d_in[0];
    const float* wkv_w = (const float*)d_in[1];
    const float* wkv_b = (const float*)d_in[2];
    const float* wtq   = (const float*)d_in[3];
    const float* alpha = (const float*)d_in[4];
    const float* qkv_w = (const float*)d_in[5];
    const float* out_w = (const float*)d_in[6];
    const float* out_b = (const float*)d_in[7];

    float* out       = (float*)d_out;
    float* sw_out    = out + (size_t)B_ * N_ * HID_;                // 33,554,432
    float* alpha_out = sw_out + (size_t)B_ * H_ * M_ * N_;          // 50,331,648
    float* zeros_out = alpha_out + H_;                              // 50,331,656
    float* attn_out  = zeros_out + H_ * M_;                         // 50,331,912

    char* ws = (char*)d_ws;
    short* kv   = (short*)(ws);                // 134,217,728 B  (B,N,2*HID) bf16
    short* swT  = (short*)(ws + 134217728);    //  33,554,432 B  (B,N,H*M)   bf16
    short* wkvT = (short*)(ws + 167772160);    //   1,048,576 B  (1024,512)  bf16
    short* Pt   = (short*)(ws + 168820736);    //   1,048,576 B  (B,512,256) bf16
    float* num  = (float*)(ws + 169869312);    //     262,144 B  (B,H,M,64)  f32
    float* wsum = (float*)(ws + 170131456);    //       4,096 B  (B,H,M)     f32
    float* qkvb = (float*)(ws + 170135552);    //     786,432 B  (B,M,1536)  f32
    float* ot   = (float*)(ws + 170921984);    //     262,144 B  (B,H,M,64)  f32

    hipMemsetAsync(num, 0, (65536 + 1024) * sizeof(float), stream);
    k_misc<<<1, 256, 0, stream>>>(alpha, alpha_out, zeros_out);
    k_wt<<<2048, 256, 0, stream>>>(wkv_w, wkvT);
    // kv = x @ wkv_w + wkv_b   (bf16 out)
    mfma_gemm<true, true><<<dim3(512, 8), 256, 0, stream>>>(
        (const void*)x, wkvT, wkv_b, (void*)kv, 512, 1024, 0, 1 << 30);
    k_slice<<<2048, 256, 0, stream>>>(kv, wtq, alpha, sw_out, swT, num, wsum);
    k_qkv<<<dim3(24, 4), 256, 0, stream>>>(num, wsum, qkv_w, qkvb);
    k_mha<<<32, 256, 0, stream>>>(qkvb, attn_out, ot);
    k_p<<<dim3(4, 32), 256, 0, stream>>>(ot, out_w, Pt);
    // out = swT @ Pt^T + out_b   (f32 out)
    mfma_gemm<false, false><<<dim3(512, 4), 256, 0, stream>>>(
        (const void*)swT, Pt, out_b, (void*)out, 256, 512, 131072, 16384);
}

// Round 2
// 732.877 us; speedup vs baseline: 1.0562x; 1.0562x over previous
//
#include <hip/hip_runtime.h>

#define B_ 4
#define N_ 16384
#define HID_ 512
#define H_ 8
#define M_ 32
#define D_ 64

typedef __attribute__((ext_vector_type(8))) short short8;
typedef __attribute__((ext_vector_type(4))) float f32x4;

__device__ __forceinline__ short f2bf(float f) {
    unsigned u = __float_as_uint(f);
    u += 0x7fffu + ((u >> 16) & 1u);
    return (short)(u >> 16);
}
__device__ __forceinline__ float bf2f(short s) {
    return __uint_as_float(((unsigned)(unsigned short)s) << 16);
}
__device__ __forceinline__ unsigned pack2(float a, float b) {
    return (unsigned)(unsigned short)f2bf(a) | ((unsigned)(unsigned short)f2bf(b) << 16);
}
__device__ __forceinline__ void gl_lds16(const short* g, short* l) {
    __builtin_amdgcn_global_load_lds((const __attribute__((address_space(1))) unsigned*)g,
                                     (__attribute__((address_space(3))) unsigned*)l, 16, 0, 0);
}

// ---------------------------------------------------------------- misc outputs
__global__ void k_misc(const float* __restrict__ alpha, float* __restrict__ a_out,
                       float* __restrict__ z_out) {
    int t = threadIdx.x;
    if (t < H_) a_out[t] = alpha[t];
    z_out[t] = 0.f;  // 256 = H_*M_
}

// --------------------------------------------- x (f32) -> bf16, streaming convert
__global__ void k_cvt(const float* __restrict__ src, short* __restrict__ dst) {
    int i = blockIdx.x * 256 + threadIdx.x;   // 8 elements per thread
    const f32x4* s = (const f32x4*)(src) + (size_t)i * 2;
    f32x4 a = s[0], b = s[1];
    short8 o;
    o[0] = f2bf(a[0]); o[1] = f2bf(a[1]); o[2] = f2bf(a[2]); o[3] = f2bf(a[3]);
    o[4] = f2bf(b[0]); o[5] = f2bf(b[1]); o[6] = f2bf(b[2]); o[7] = f2bf(b[3]);
    ((short8*)dst)[i] = o;
}

// ------------------------------------------- wkv_w (512x1024 f32) -> (1024x512 bf16)
__global__ void k_wt(const float* __restrict__ w, short* __restrict__ wt) {
    int e = blockIdx.x * 256 + threadIdx.x;   // 524288 total
    int nn = e >> 9, kk = e & 511;
    wt[e] = f2bf(w[kk * 1024 + nn]);
}

// ---------------------------------------------------------------- MFMA GEMM (m97 structure)
// C (rows x Ncols) = A (rows x K, bf16) * Bt^T (Bt: Ncols x K bf16) + bias
// grid: (x = col tiles, y = row tiles). 128x128 tile, BK=32, global_load_lds width 16.
template <bool OUT_BF16>
__global__ __launch_bounds__(256, 2)
void mfma_gemm(const short* __restrict__ A, const short* __restrict__ Bt,
               const float* __restrict__ bias, void* __restrict__ Cv,
               int K, int Ncols, int b_stride, int rows_per_b) {
    __shared__ short As[128 * 32];
    __shared__ short Bs[128 * 32];
    const int t = threadIdx.x;
    const int col0 = blockIdx.x * 128;
    const int row0 = blockIdx.y * 128;
    const short* Bblk = Bt;
    if (b_stride) Bblk += (size_t)(row0 / rows_per_b) * (size_t)b_stride;

    // staging geometry: lane handles 16B at tile element offset (p*256+t)*8
    const int r_a = t >> 2;            // row within tile (+64 for p=1)
    const int c_a = (t & 3) << 3;      // k within BK
    const short* Ap = A + (size_t)(row0 + r_a) * K + c_a;
    const short* Bp = Bblk + (size_t)(col0 + r_a) * K + c_a;
    short* As0 = &As[t << 3];
    short* Bs0 = &Bs[t << 3];
    const size_t rowskip = (size_t)64 * K;

    const int w = t >> 6;
    const int L = t & 63;
    const int wm = (w >> 1) << 6;
    const int wn = (w & 1) << 6;
    const int lm = L & 15;
    const int lq = L >> 4;

    f32x4 acc[4][4];
#pragma unroll
    for (int i = 0; i < 4; ++i)
#pragma unroll
        for (int j = 0; j < 4; ++j) acc[i][j] = (f32x4){0.f, 0.f, 0.f, 0.f};

    for (int k0 = 0; k0 < K; k0 += 32) {
        gl_lds16(Ap + k0, As0);
        gl_lds16(Ap + k0 + rowskip, As0 + 2048);
        gl_lds16(Bp + k0, Bs0);
        gl_lds16(Bp + k0 + rowskip, Bs0 + 2048);
        __syncthreads();
        short8 af[4], bfr[4];
#pragma unroll
        for (int i = 0; i < 4; ++i)
            af[i] = *(const short8*)&As[((wm + (i << 4) + lm) << 5) + (lq << 3)];
#pragma unroll
        for (int j = 0; j < 4; ++j)
            bfr[j] = *(const short8*)&Bs[((wn + (j << 4) + lm) << 5) + (lq << 3)];
#pragma unroll
        for (int i = 0; i < 4; ++i)
#pragma unroll
            for (int j = 0; j < 4; ++j)
                acc[i][j] = __builtin_amdgcn_mfma_f32_16x16x32_bf16(af[i], bfr[j], acc[i][j], 0, 0, 0);
        __syncthreads();
    }
#pragma unroll
    for (int i = 0; i < 4; ++i) {
#pragma unroll
        for (int j = 0; j < 4; ++j) {
            const int gr = row0 + wm + (i << 4) + (lq << 2);
            const int gc = col0 + wn + (j << 4) + lm;
            const float bv = bias[gc];
#pragma unroll
            for (int r = 0; r < 4; ++r) {
                float v = acc[i][j][r] + bv;
                if constexpr (OUT_BF16)
                    ((short*)Cv)[(size_t)(gr + r) * Ncols + gc] = f2bf(v);
                else
                    ((float*)Cv)[(size_t)(gr + r) * Ncols + gc] = v;
            }
        }
    }
}

// ---------------------------------------------------------------- slice kernel
// Per block: one (b,h), 256-token chunk. Scores, softmax over m, writes sw (f32 out)
// + swT (bf16 ws), accumulates num[b,h,m,d] and wsum[b,h,m].
// LDS: xv XOR-swizzled (32KB) + packed bf16 weight pairs stride 17 (17.4KB) -> 3 blocks/CU.
__global__ __launch_bounds__(256, 3)
void k_slice(const short* __restrict__ kv, const float* __restrict__ wtq,
             const float* __restrict__ alpha, float* __restrict__ sw_out,
             short* __restrict__ swT, float* __restrict__ num, float* __restrict__ wsum) {
    __shared__ short8 xv_s[256 * 8];      // 32 KB, slot i stored at i^(t&7)
    __shared__ unsigned w2_s[256 * 17];   // 17408 B, bf16 pairs (m, m+1)
    const int t = threadIdx.x;
    const int bx = blockIdx.x;
    const int chunk = bx & 63;
    const int h = (bx >> 6) & 7;
    const int b = bx >> 9;
    const int n = chunk * 256 + t;
    const size_t rowbase = (size_t)(b * N_ + n) * (2 * HID_);

    // stage xv row (bf16, swizzled)
    const short8* xvp = (const short8*)(kv + rowbase + HID_ + h * 64);
#pragma unroll
    for (int i = 0; i < 8; ++i) xv_s[t * 8 + (i ^ (t & 7))] = xvp[i];

    // xk row into registers
    float x[64];
    const short8* xkp = (const short8*)(kv + rowbase + h * 64);
#pragma unroll
    for (int i = 0; i < 8; ++i) {
        short8 v = xkp[i];
#pragma unroll
        for (int j = 0; j < 8; ++j) x[i * 8 + j] = bf2f(v[j]);
    }

    // scores: wtq reads are block-uniform -> scalar loads
    const float* wq = wtq + h * (M_ * 64);
    float s[32];
#pragma unroll
    for (int m = 0; m < 32; ++m) {
        float a = 0.f;
#pragma unroll
        for (int d = 0; d < 64; ++d) a += wq[m * 64 + d] * x[d];
        s[m] = a;
    }
    const float al = alpha[h];
    float mx = -1e30f;
#pragma unroll
    for (int m = 0; m < 32; ++m) { s[m] *= al; mx = fmaxf(mx, s[m]); }
    float sum = 0.f;
#pragma unroll
    for (int m = 0; m < 32; ++m) { s[m] = __expf(s[m] - mx); sum += s[m]; }
    const float inv = 1.f / sum;

    float* swp = sw_out + (size_t)(b * H_ + h) * M_ * N_ + n;
    short* swtp = swT + (size_t)(b * N_ + n) * (H_ * M_) + h * M_;
#pragma unroll
    for (int mp = 0; mp < 16; ++mp) {
        float w0 = s[2 * mp] * inv;
        float w1 = s[2 * mp + 1] * inv;
        swp[(size_t)(2 * mp) * N_] = w0;       // coalesced over t
        swp[(size_t)(2 * mp + 1) * N_] = w1;
        unsigned pk = pack2(w0, w1);
        *(unsigned*)(swtp + 2 * mp) = pk;
        w2_s[t * 17 + mp] = pk;
    }
    __syncthreads();

    // block-local weighted sum: num[m][d] += sum_t w[t][m] * xv[t][d]
    const int m = t >> 3;
    const int dg = t & 7;
    const int mp = m >> 1;
    const int sh = (m & 1) ? 0 : 16;
    float acc[8] = {0, 0, 0, 0, 0, 0, 0, 0};
    float wsl = 0.f;
#pragma unroll 4
    for (int tt = 0; tt < 256; ++tt) {
        unsigned wp = w2_s[tt * 17 + mp];
        short8 v8 = xv_s[tt * 8 + (dg ^ (tt & 7))];
        float wv = __uint_as_float((wp << sh) & 0xffff0000u);
        wsl += wv;
#pragma unroll
        for (int q = 0; q < 8; ++q) acc[q] += wv * bf2f(v8[q]);
    }
    float* np = num + ((size_t)(b * H_ + h) * M_ + m) * 64 + dg * 8;
#pragma unroll
    for (int q = 0; q < 8; ++q) atomicAdd(np + q, acc[q]);
    if (dg == 0) atomicAdd(wsum + (b * H_ + h) * M_ + m, wsl);
}

// ---------------------------------------------------------------- qkv GEMM (tiny)
__global__ __launch_bounds__(256, 2)
void k_qkv(const float* __restrict__ num, const float* __restrict__ wsum,
           const float* __restrict__ qkv_w, float* __restrict__ qkv) {
    __shared__ float st_s[512 * 32];  // [k][m], 64 KB
    const int t = threadIdx.x;
    const int b = blockIdx.y;
    for (int p = 0; p < 64; ++p) {
        int idx = p * 256 + t;
        int m = idx & 31, k = idx >> 5;
        int h = k >> 6, d = k & 63;
        float wsv = wsum[(b * H_ + h) * M_ + m];
        st_s[k * 32 + m] = num[((size_t)(b * H_ + h) * M_ + m) * 64 + d] / (wsv + 1e-5f);
    }
    __syncthreads();
    const int m = t >> 3;
    const int c0 = blockIdx.x * 64 + (t & 7) * 8;
    float acc[8] = {};
    for (int k = 0; k < 512; ++k) {
        float sv = st_s[k * 32 + m];
        const f32x4* wp = (const f32x4*)(qkv_w + (size_t)k * 1536 + c0);
        f32x4 w0 = wp[0], w1 = wp[1];
        acc[0] += sv * w0[0]; acc[1] += sv * w0[1]; acc[2] += sv * w0[2]; acc[3] += sv * w0[3];
        acc[4] += sv * w1[0]; acc[5] += sv * w1[1]; acc[6] += sv * w1[2]; acc[7] += sv * w1[3];
    }
    float* dst = qkv + (size_t)(b * M_ + m) * 1536 + c0;
#pragma unroll
    for (int i = 0; i < 8; ++i) dst[i] = acc[i];
}

// ---------------------------------------------------------------- MHA (tiny, M=32)
__global__ __launch_bounds__(256)
void k_mha(const float* __restrict__ qkv, float* __restrict__ attn_out,
           float* __restrict__ ot) {
    __shared__ float q_s[32 * 65], k_s[32 * 65], v_s[32 * 65];
    __shared__ float s_s[32 * 33], p_s[32 * 33];
    const int bx = blockIdx.x;
    const int b = bx >> 3, h = bx & 7;
    const int t = threadIdx.x;
    for (int p = 0; p < 8; ++p) {
        int idx = p * 256 + t;
        int m = idx >> 6, d = idx & 63;
        size_t base = (size_t)(b * M_ + m) * 1536 + h * 64 + d;
        q_s[m * 65 + d] = qkv[base];
        k_s[m * 65 + d] = qkv[base + 512];
        v_s[m * 65 + d] = qkv[base + 1024];
    }
    __syncthreads();
    for (int p = 0; p < 4; ++p) {
        int c = p * 256 + t;
        int m = c >> 5, mm = c & 31;
        float a = 0.f;
#pragma unroll
        for (int d = 0; d < 64; ++d) a += q_s[m * 65 + d] * k_s[mm * 65 + d];
        s_s[m * 33 + mm] = a * 0.125f;
    }
    __syncthreads();
    if (t < 32) {
        float mx = -1e30f;
        for (int mm = 0; mm < 32; ++mm) mx = fmaxf(mx, s_s[t * 33 + mm]);
        float sum = 0.f;
        for (int mm = 0; mm < 32; ++mm) {
            float e = __expf(s_s[t * 33 + mm] - mx);
            p_s[t * 33 + mm] = e;
            sum += e;
        }
        float inv = 1.f / sum;
        for (int mm = 0; mm < 32; ++mm) {
            float av = p_s[t * 33 + mm] * inv;
            p_s[t * 33 + mm] = av;
            attn_out[((size_t)(b * H_ + h) * M_ + t) * M_ + mm] = av;
        }
    }
    __syncthreads();
    const int m = t >> 3, d0 = (t & 7) * 8;
    float acc[8] = {};
    for (int mm = 0; mm < 32; ++mm) {
        float av = p_s[m * 33 + mm];
#pragma unroll
        for (int j = 0; j < 8; ++j) acc[j] += av * v_s[mm * 65 + d0 + j];
    }
    float* dst = ot + ((size_t)(b * H_ + h) * M_ + m) * 64 + d0;
#pragma unroll
    for (int j = 0; j < 8; ++j) dst[j] = acc[j];
}

// ------------------------------------- P^T: Pt[b][j][h*32+m] = sum_d ot[m][d]*out_w[h*64+d][j]
__global__ __launch_bounds__(256)
void k_p(const float* __restrict__ ot, const float* __restrict__ out_w,
         short* __restrict__ Pt) {
    __shared__ float ot_s[32 * 65];
    const int bh = blockIdx.y;
    const int b = bh >> 3, h = bh & 7;
    const int t = threadIdx.x;
    for (int p = 0; p < 8; ++p) {
        int idx = p * 256 + t;
        int m = idx >> 6, d = idx & 63;
        ot_s[m * 65 + d] = ot[(size_t)bh * (M_ * 64) + idx];
    }
    __syncthreads();
    const int j = blockIdx.x * 128 + (t & 127);
    const int mh = (t >> 7) * 16;
    float acc[16] = {};
    for (int d = 0; d < 64; ++d) {
        float ow = out_w[(size_t)(h * 64 + d) * HID_ + j];   // coalesced
#pragma unroll
        for (int i = 0; i < 16; ++i) acc[i] += ot_s[(mh + i) * 65 + d] * ow;
    }
    short* dst = Pt + ((size_t)b * HID_ + j) * (H_ * M_) + h * M_ + mh;
#pragma unroll
    for (int i = 0; i < 16; i += 2) *(unsigned*)(dst + i) = pack2(acc[i], acc[i + 1]);
}

// ---------------------------------------------------------------- launcher
extern "C" void kernel_launch(void* const* d_in, const int* in_sizes, int n_in,
                              void* d_out, int out_size, void* d_ws, size_t ws_size,
                              hipStream_t stream) {
    const float* x     = (const float*)d_in[0];
    const float* wkv_w = (const float*)d_in[1];
    const float* wkv_b = (const float*)d_in[2];
    const float* wtq   = (const float*)d_in[3];
    const float* alpha = (const float*)d_in[4];
    const float* qkv_w = (const float*)d_in[5];
    const float* out_w = (const float*)d_in[6];
    const float* out_b = (const float*)d_in[7];

    float* out       = (float*)d_out;
    float* sw_out    = out + (size_t)B_ * N_ * HID_;                // 33,554,432
    float* alpha_out = sw_out + (size_t)B_ * H_ * M_ * N_;          // 50,331,648
    float* zeros_out = alpha_out + H_;                              // 50,331,656
    float* attn_out  = zeros_out + H_ * M_;                         // 50,331,912

    // x_bf overlays the sw_out output region (dead until k_slice writes it later
    // in the same launch) — no extra workspace needed.
    short* x_bf = (short*)sw_out;                                   // 67,108,864 B

    char* ws = (char*)d_ws;
    short* kv   = (short*)(ws);                // 134,217,728 B  (B,N,2*HID) bf16
    short* swT  = (short*)(ws + 134217728);    //  33,554,432 B  (B,N,H*M)   bf16
    short* wkvT = (short*)(ws + 167772160);    //   1,048,576 B  (1024,512)  bf16
    short* Pt   = (short*)(ws + 168820736);    //   1,048,576 B  (B,512,256) bf16
    float* num  = (float*)(ws + 169869312);    //     262,144 B  (B,H,M,64)  f32
    float* wsum = (float*)(ws + 170131456);    //       4,096 B  (B,H,M)     f32
    float* qkvb = (float*)(ws + 170135552);    //     786,432 B  (B,M,1536)  f32
    float* ot   = (float*)(ws + 170921984);    //     262,144 B  (B,H,M,64)  f32

    hipMemsetAsync(num, 0, (65536 + 1024) * sizeof(float), stream);
    k_misc<<<1, 256, 0, stream>>>(alpha, alpha_out, zeros_out);
    k_cvt<<<16384, 256, 0, stream>>>(x, x_bf);
    k_wt<<<2048, 256, 0, stream>>>(wkv_w, wkvT);
    // kv = x @ wkv_w + wkv_b   (bf16 out)
    mfma_gemm<true><<<dim3(8, 512), 256, 0, stream>>>(
        x_bf, wkvT, wkv_b, (void*)kv, 512, 1024, 0, 1 << 30);
    k_slice<<<2048, 256, 0, stream>>>(kv, wtq, alpha, sw_out, swT, num, wsum);
    k_qkv<<<dim3(24, 4), 256, 0, stream>>>(num, wsum, qkv_w, qkvb);
    k_mha<<<32, 256, 0, stream>>>(qkvb, attn_out, ot);
    k_p<<<dim3(4, 32), 256, 0, stream>>>(ot, out_w, Pt);
    // out = swT @ Pt^T + out_b   (f32 out)
    mfma_gemm<false><<<dim3(4, 512), 256, 0, stream>>>(
        swT, Pt, out_b, (void*)out, 256, 512, 131072, 16384);
}

// Round 3
// 724.150 us; speedup vs baseline: 1.0689x; 1.0121x over previous
//
#include <hip/hip_runtime.h>

#define B_ 4
#define N_ 16384
#define HID_ 512
#define H_ 8
#define M_ 32
#define D_ 64

typedef __attribute__((ext_vector_type(8))) short short8;
typedef __attribute__((ext_vector_type(4))) float f32x4;

__device__ __forceinline__ short f2bf(float f) {
    unsigned u = __float_as_uint(f);
    u += 0x7fffu + ((u >> 16) & 1u);
    return (short)(u >> 16);
}
__device__ __forceinline__ float bf2f(short s) {
    return __uint_as_float(((unsigned)(unsigned short)s) << 16);
}
__device__ __forceinline__ unsigned pack2(float a, float b) {
    return (unsigned)(unsigned short)f2bf(a) | ((unsigned)(unsigned short)f2bf(b) << 16);
}
__device__ __forceinline__ void gl_lds16(const short* g, short* l) {
    __builtin_amdgcn_global_load_lds((const __attribute__((address_space(1))) unsigned*)g,
                                     (__attribute__((address_space(3))) unsigned*)l, 16, 0, 0);
}

// ---------------------------------------------------------------- misc outputs
__global__ void k_misc(const float* __restrict__ alpha, float* __restrict__ a_out,
                       float* __restrict__ z_out) {
    int t = threadIdx.x;
    if (t < H_) a_out[t] = alpha[t];
    z_out[t] = 0.f;  // 256 = H_*M_
}

// --------------------------------------------- x (f32) -> bf16, streaming convert
__global__ void k_cvt(const float* __restrict__ src, short* __restrict__ dst) {
    int i = blockIdx.x * 256 + threadIdx.x;   // 8 elements per thread
    const f32x4* s = (const f32x4*)(src) + (size_t)i * 2;
    f32x4 a = s[0], b = s[1];
    short8 o;
    o[0] = f2bf(a[0]); o[1] = f2bf(a[1]); o[2] = f2bf(a[2]); o[3] = f2bf(a[3]);
    o[4] = f2bf(b[0]); o[5] = f2bf(b[1]); o[6] = f2bf(b[2]); o[7] = f2bf(b[3]);
    ((short8*)dst)[i] = o;
}

// ------------------------------------------- wkv_w (512x1024 f32) -> (1024x512 bf16)
__global__ void k_wt(const float* __restrict__ w, short* __restrict__ wt) {
    int e = blockIdx.x * 256 + threadIdx.x;   // 524288 total
    int nn = e >> 9, kk = e & 511;
    wt[e] = f2bf(w[kk * 1024 + nn]);
}

// ---------------------------------------------------------------- MFMA GEMM (m97 structure)
// C (rows x Ncols) = A (rows x K, bf16) * Bt^T (Bt: Ncols x K bf16) + bias
// grid: (x = col tiles, y = row tiles). 128x128 tile, BK=32, global_load_lds width 16.
template <bool OUT_BF16>
__global__ __launch_bounds__(256, 2)
void mfma_gemm(const short* __restrict__ A, const short* __restrict__ Bt,
               const float* __restrict__ bias, void* __restrict__ Cv,
               int K, int Ncols, int b_stride, int rows_per_b) {
    __shared__ short As[128 * 32];
    __shared__ short Bs[128 * 32];
    const int t = threadIdx.x;
    const int col0 = blockIdx.x * 128;
    const int row0 = blockIdx.y * 128;
    const short* Bblk = Bt;
    if (b_stride) Bblk += (size_t)(row0 / rows_per_b) * (size_t)b_stride;

    const int r_a = t >> 2;            // row within tile (+64 for p=1)
    const int c_a = (t & 3) << 3;      // k within BK
    const short* Ap = A + (size_t)(row0 + r_a) * K + c_a;
    const short* Bp = Bblk + (size_t)(col0 + r_a) * K + c_a;
    short* As0 = &As[t << 3];
    short* Bs0 = &Bs[t << 3];
    const size_t rowskip = (size_t)64 * K;

    const int w = t >> 6;
    const int L = t & 63;
    const int wm = (w >> 1) << 6;
    const int wn = (w & 1) << 6;
    const int lm = L & 15;
    const int lq = L >> 4;

    f32x4 acc[4][4];
#pragma unroll
    for (int i = 0; i < 4; ++i)
#pragma unroll
        for (int j = 0; j < 4; ++j) acc[i][j] = (f32x4){0.f, 0.f, 0.f, 0.f};

    for (int k0 = 0; k0 < K; k0 += 32) {
        gl_lds16(Ap + k0, As0);
        gl_lds16(Ap + k0 + rowskip, As0 + 2048);
        gl_lds16(Bp + k0, Bs0);
        gl_lds16(Bp + k0 + rowskip, Bs0 + 2048);
        __syncthreads();
        short8 af[4], bfr[4];
#pragma unroll
        for (int i = 0; i < 4; ++i)
            af[i] = *(const short8*)&As[((wm + (i << 4) + lm) << 5) + (lq << 3)];
#pragma unroll
        for (int j = 0; j < 4; ++j)
            bfr[j] = *(const short8*)&Bs[((wn + (j << 4) + lm) << 5) + (lq << 3)];
#pragma unroll
        for (int i = 0; i < 4; ++i)
#pragma unroll
            for (int j = 0; j < 4; ++j)
                acc[i][j] = __builtin_amdgcn_mfma_f32_16x16x32_bf16(af[i], bfr[j], acc[i][j], 0, 0, 0);
        __syncthreads();
    }
#pragma unroll
    for (int i = 0; i < 4; ++i) {
#pragma unroll
        for (int j = 0; j < 4; ++j) {
            const int gr = row0 + wm + (i << 4) + (lq << 2);
            const int gc = col0 + wn + (j << 4) + lm;
            const float bv = bias[gc];
#pragma unroll
            for (int r = 0; r < 4; ++r) {
                float v = acc[i][j][r] + bv;
                if constexpr (OUT_BF16)
                    ((short*)Cv)[(size_t)(gr + r) * Ncols + gc] = f2bf(v);
                else
                    ((float*)Cv)[(size_t)(gr + r) * Ncols + gc] = v;
            }
        }
    }
}

// ---------------------------------------------------------------- slice kernel
// Per block: one (b,h), 256-token chunk. Scores, softmax over m, writes sw (f32 out)
// + swT (bf16 ws), accumulates num[b,h,m,d] and wsum[b,h,m].
// Register discipline: xk kept packed bf16 (32 VGPRs), scores computed in 4 blocks
// of 16 d-values (only 16 unpacked floats live) -> ~100 VGPRs, no spill.
// LDS 50KB -> 3 blocks/CU; occupancy pinned with waves_per_eu(3,3) so LLVM doesn't
// shrink VGPRs below need and spill (R2: VGPR=68, 137MB scratch traffic).
__global__ __attribute__((amdgpu_flat_work_group_size(256, 256), amdgpu_waves_per_eu(3, 3)))
void k_slice(const short* __restrict__ kv, const float* __restrict__ wtq,
             const float* __restrict__ alpha, float* __restrict__ sw_out,
             short* __restrict__ swT, float* __restrict__ num, float* __restrict__ wsum) {
    __shared__ short8 xv_s[256 * 8];      // 32 KB, slot i stored at i^(t&7)
    __shared__ unsigned w2_s[256 * 17];   // 17408 B, bf16 pairs (m, m+1)
    const int t = threadIdx.x;
    const int bx = blockIdx.x;
    const int chunk = bx & 63;
    const int h = (bx >> 6) & 7;
    const int b = bx >> 9;
    const int n = chunk * 256 + t;
    const size_t rowbase = (size_t)(b * N_ + n) * (2 * HID_);

    // xk row, packed bf16 (8 x b128 = 32 VGPRs)
    short8 xk8[8];
    const short8* xkp = (const short8*)(kv + rowbase + h * 64);
#pragma unroll
    for (int i = 0; i < 8; ++i) xk8[i] = xkp[i];

    // stage xv row (bf16, swizzled)
    const short8* xvp = (const short8*)(kv + rowbase + HID_ + h * 64);
#pragma unroll
    for (int i = 0; i < 8; ++i) xv_s[t * 8 + (i ^ (t & 7))] = xvp[i];

    // scores in 4 d-blocks of 16: only xd[16] unpacked floats live at a time.
    const float* wq = wtq + h * (M_ * 64);
    float s[32];
#pragma unroll
    for (int m = 0; m < 32; ++m) s[m] = 0.f;
#pragma unroll
    for (int blk = 0; blk < 4; ++blk) {
        float xd[16];
#pragma unroll
        for (int j = 0; j < 8; ++j) {
            xd[j] = bf2f(xk8[2 * blk][j]);
            xd[8 + j] = bf2f(xk8[2 * blk + 1][j]);
        }
#pragma unroll
        for (int m = 0; m < 32; ++m) {
            float a = 0.f;
#pragma unroll
            for (int d = 0; d < 16; ++d) a += wq[m * 64 + blk * 16 + d] * xd[d];
            s[m] += a;
        }
    }
    const float al = alpha[h];
    float mx = -1e30f;
#pragma unroll
    for (int m = 0; m < 32; ++m) { s[m] *= al; mx = fmaxf(mx, s[m]); }
    float sum = 0.f;
#pragma unroll
    for (int m = 0; m < 32; ++m) { s[m] = __expf(s[m] - mx); sum += s[m]; }
    const float inv = 1.f / sum;

    float* swp = sw_out + (size_t)(b * H_ + h) * M_ * N_ + n;
    unsigned pk[16];
#pragma unroll
    for (int mp = 0; mp < 16; ++mp) {
        float w0 = s[2 * mp] * inv;
        float w1 = s[2 * mp + 1] * inv;
        swp[(size_t)(2 * mp) * N_] = w0;       // coalesced over t
        swp[(size_t)(2 * mp + 1) * N_] = w1;
        pk[mp] = pack2(w0, w1);
        w2_s[t * 17 + mp] = pk[mp];
    }
    // swT row: 4 x 16B stores instead of 16 x 4B
    short8* swtp = (short8*)(swT + (size_t)(b * N_ + n) * (H_ * M_) + h * M_);
#pragma unroll
    for (int q = 0; q < 4; ++q) {
        short8 v;
        v[0] = (short)(pk[4 * q] & 0xffff);     v[1] = (short)(pk[4 * q] >> 16);
        v[2] = (short)(pk[4 * q + 1] & 0xffff); v[3] = (short)(pk[4 * q + 1] >> 16);
        v[4] = (short)(pk[4 * q + 2] & 0xffff); v[5] = (short)(pk[4 * q + 2] >> 16);
        v[6] = (short)(pk[4 * q + 3] & 0xffff); v[7] = (short)(pk[4 * q + 3] >> 16);
        swtp[q] = v;
    }
    __syncthreads();

    // block-local weighted sum: num[m][d] += sum_t w[t][m] * xv[t][d]
    const int m = t >> 3;
    const int dg = t & 7;
    const int mp = m >> 1;
    const int sh = (m & 1) ? 0 : 16;
    float acc[8] = {0, 0, 0, 0, 0, 0, 0, 0};
    float wsl = 0.f;
#pragma unroll 4
    for (int tt = 0; tt < 256; ++tt) {
        unsigned wp = w2_s[tt * 17 + mp];
        short8 v8 = xv_s[tt * 8 + (dg ^ (tt & 7))];
        float wv = __uint_as_float((wp << sh) & 0xffff0000u);
        wsl += wv;
#pragma unroll
        for (int q = 0; q < 8; ++q) acc[q] += wv * bf2f(v8[q]);
    }
    float* np = num + ((size_t)(b * H_ + h) * M_ + m) * 64 + dg * 8;
#pragma unroll
    for (int q = 0; q < 8; ++q) atomicAdd(np + q, acc[q]);
    if (dg == 0) atomicAdd(wsum + (b * H_ + h) * M_ + m, wsl);
}

// ---------------------------------------------------------------- qkv GEMM (tiny)
__global__ __launch_bounds__(256, 2)
void k_qkv(const float* __restrict__ num, const float* __restrict__ wsum,
           const float* __restrict__ qkv_w, float* __restrict__ qkv) {
    __shared__ float st_s[512 * 32];  // [k][m], 64 KB
    const int t = threadIdx.x;
    const int b = blockIdx.y;
    for (int p = 0; p < 64; ++p) {
        int idx = p * 256 + t;
        int m = idx & 31, k = idx >> 5;
        int h = k >> 6, d = k & 63;
        float wsv = wsum[(b * H_ + h) * M_ + m];
        st_s[k * 32 + m] = num[((size_t)(b * H_ + h) * M_ + m) * 64 + d] / (wsv + 1e-5f);
    }
    __syncthreads();
    const int m = t >> 3;
    const int c0 = blockIdx.x * 64 + (t & 7) * 8;
    float acc[8] = {};
    for (int k = 0; k < 512; ++k) {
        float sv = st_s[k * 32 + m];
        const f32x4* wp = (const f32x4*)(qkv_w + (size_t)k * 1536 + c0);
        f32x4 w0 = wp[0], w1 = wp[1];
        acc[0] += sv * w0[0]; acc[1] += sv * w0[1]; acc[2] += sv * w0[2]; acc[3] += sv * w0[3];
        acc[4] += sv * w1[0]; acc[5] += sv * w1[1]; acc[6] += sv * w1[2]; acc[7] += sv * w1[3];
    }
    float* dst = qkv + (size_t)(b * M_ + m) * 1536 + c0;
#pragma unroll
    for (int i = 0; i < 8; ++i) dst[i] = acc[i];
}

// ---------------------------------------------------------------- MHA (tiny, M=32)
__global__ __launch_bounds__(256)
void k_mha(const float* __restrict__ qkv, float* __restrict__ attn_out,
           float* __restrict__ ot) {
    __shared__ float q_s[32 * 65], k_s[32 * 65], v_s[32 * 65];
    __shared__ float s_s[32 * 33], p_s[32 * 33];
    const int bx = blockIdx.x;
    const int b = bx >> 3, h = bx & 7;
    const int t = threadIdx.x;
    for (int p = 0; p < 8; ++p) {
        int idx = p * 256 + t;
        int m = idx >> 6, d = idx & 63;
        size_t base = (size_t)(b * M_ + m) * 1536 + h * 64 + d;
        q_s[m * 65 + d] = qkv[base];
        k_s[m * 65 + d] = qkv[base + 512];
        v_s[m * 65 + d] = qkv[base + 1024];
    }
    __syncthreads();
    for (int p = 0; p < 4; ++p) {
        int c = p * 256 + t;
        int m = c >> 5, mm = c & 31;
        float a = 0.f;
#pragma unroll
        for (int d = 0; d < 64; ++d) a += q_s[m * 65 + d] * k_s[mm * 65 + d];
        s_s[m * 33 + mm] = a * 0.125f;
    }
    __syncthreads();
    if (t < 32) {
        float mx = -1e30f;
        for (int mm = 0; mm < 32; ++mm) mx = fmaxf(mx, s_s[t * 33 + mm]);
        float sum = 0.f;
        for (int mm = 0; mm < 32; ++mm) {
            float e = __expf(s_s[t * 33 + mm] - mx);
            p_s[t * 33 + mm] = e;
            sum += e;
        }
        float inv = 1.f / sum;
        for (int mm = 0; mm < 32; ++mm) {
            float av = p_s[t * 33 + mm] * inv;
            p_s[t * 33 + mm] = av;
            attn_out[((size_t)(b * H_ + h) * M_ + t) * M_ + mm] = av;
        }
    }
    __syncthreads();
    const int m = t >> 3, d0 = (t & 7) * 8;
    float acc[8] = {};
    for (int mm = 0; mm < 32; ++mm) {
        float av = p_s[m * 33 + mm];
#pragma unroll
        for (int j = 0; j < 8; ++j) acc[j] += av * v_s[mm * 65 + d0 + j];
    }
    float* dst = ot + ((size_t)(b * H_ + h) * M_ + m) * 64 + d0;
#pragma unroll
    for (int j = 0; j < 8; ++j) dst[j] = acc[j];
}

// ------------------------------------- P^T: Pt[b][j][h*32+m] = sum_d ot[m][d]*out_w[h*64+d][j]
__global__ __launch_bounds__(256)
void k_p(const float* __restrict__ ot, const float* __restrict__ out_w,
         short* __restrict__ Pt) {
    __shared__ float ot_s[32 * 65];
    const int bh = blockIdx.y;
    const int b = bh >> 3, h = bh & 7;
    const int t = threadIdx.x;
    for (int p = 0; p < 8; ++p) {
        int idx = p * 256 + t;
        int m = idx >> 6, d = idx & 63;
        ot_s[m * 65 + d] = ot[(size_t)bh * (M_ * 64) + idx];
    }
    __syncthreads();
    const int j = blockIdx.x * 128 + (t & 127);
    const int mh = (t >> 7) * 16;
    float acc[16] = {};
    for (int d = 0; d < 64; ++d) {
        float ow = out_w[(size_t)(h * 64 + d) * HID_ + j];   // coalesced
#pragma unroll
        for (int i = 0; i < 16; ++i) acc[i] += ot_s[(mh + i) * 65 + d] * ow;
    }
    short* dst = Pt + ((size_t)b * HID_ + j) * (H_ * M_) + h * M_ + mh;
#pragma unroll
    for (int i = 0; i < 16; i += 2) *(unsigned*)(dst + i) = pack2(acc[i], acc[i + 1]);
}

// ---------------------------------------------------------------- launcher
extern "C" void kernel_launch(void* const* d_in, const int* in_sizes, int n_in,
                              void* d_out, int out_size, void* d_ws, size_t ws_size,
                              hipStream_t stream) {
    const float* x     = (const float*)d_in[0];
    const float* wkv_w = (const float*)d_in[1];
    const float* wkv_b = (const float*)d_in[2];
    const float* wtq   = (const float*)d_in[3];
    const float* alpha = (const float*)d_in[4];
    const float* qkv_w = (const float*)d_in[5];
    const float* out_w = (const float*)d_in[6];
    const float* out_b = (const float*)d_in[7];

    float* out       = (float*)d_out;
    float* sw_out    = out + (size_t)B_ * N_ * HID_;                // 33,554,432
    float* alpha_out = sw_out + (size_t)B_ * H_ * M_ * N_;          // 50,331,648
    float* zeros_out = alpha_out + H_;                              // 50,331,656
    float* attn_out  = zeros_out + H_ * M_;                         // 50,331,912

    // x_bf overlays the sw_out output region (dead until k_slice writes it later
    // in the same launch) — no extra workspace needed.
    short* x_bf = (short*)sw_out;                                   // 67,108,864 B

    char* ws = (char*)d_ws;
    short* kv   = (short*)(ws);                // 134,217,728 B  (B,N,2*HID) bf16
    short* swT  = (short*)(ws + 134217728);    //  33,554,432 B  (B,N,H*M)   bf16
    short* wkvT = (short*)(ws + 167772160);    //   1,048,576 B  (1024,512)  bf16
    short* Pt   = (short*)(ws + 168820736);    //   1,048,576 B  (B,512,256) bf16
    float* num  = (float*)(ws + 169869312);    //     262,144 B  (B,H,M,64)  f32
    float* wsum = (float*)(ws + 170131456);    //       4,096 B  (B,H,M)     f32
    float* qkvb = (float*)(ws + 170135552);    //     786,432 B  (B,M,1536)  f32
    float* ot   = (float*)(ws + 170921984);    //     262,144 B  (B,H,M,64)  f32

    hipMemsetAsync(num, 0, (65536 + 1024) * sizeof(float), stream);
    k_misc<<<1, 256, 0, stream>>>(alpha, alpha_out, zeros_out);
    k_cvt<<<16384, 256, 0, stream>>>(x, x_bf);
    k_wt<<<2048, 256, 0, stream>>>(wkv_w, wkvT);
    // kv = x @ wkv_w + wkv_b   (bf16 out)
    mfma_gemm<true><<<dim3(8, 512), 256, 0, stream>>>(
        x_bf, wkvT, wkv_b, (void*)kv, 512, 1024, 0, 1 << 30);
    k_slice<<<2048, 256, 0, stream>>>(kv, wtq, alpha, sw_out, swT, num, wsum);
    k_qkv<<<dim3(24, 4), 256, 0, stream>>>(num, wsum, qkv_w, qkvb);
    k_mha<<<32, 256, 0, stream>>>(qkvb, attn_out, ot);
    k_p<<<dim3(4, 32), 256, 0, stream>>>(ot, out_w, Pt);
    // out = swT @ Pt^T + out_b   (f32 out)
    mfma_gemm<false><<<dim3(4, 512), 256, 0, stream>>>(
        swT, Pt, out_b, (void*)out, 256, 512, 131072, 16384);
}